// Round 14
// baseline (19077.461 us; speedup 1.0000x reference)
//
#include <hip/hip_runtime.h>
#include <hip/hip_bf16.h>
#include <math.h>

#define NCB 8
#define CBS 1024
#define HID 512
#define NB 8
#define TLAT 4096
#define DELTA 6.0e-5f

__global__ void re_sentinel(float* out, float v)
{
    out[threadIdx.x] = v;
}

// ---------------- encoder conv: stride 2, pad 7, K=15, ELU — f64 interior, f32 storage ----
// Thread handles outputs {t0+tid, t0+tid+256}: parity-split LDS reads are stride-1
// (conflict-free). Per-output FMA chain (ci outer, k inner) bit-identical to r11/r13.
template<int CIN, int COUT, int LIN>
__global__ __launch_bounds__(256)
void re_enc(const float* __restrict__ x, const float* __restrict__ w,
            const float* __restrict__ bias, float* __restrict__ y)
{
    constexpr int LOUT = LIN / 2;
    __shared__ float xs[2][520];                 // parity-split halo tile
    const int tid = threadIdx.x;
    const int t0  = blockIdx.x * 512;
    const int co0 = blockIdx.y * 4;
    const int b   = blockIdx.z;
    const float* xb = x + (size_t)b * CIN * LIN;
    const int base = 2 * t0 - 8;                 // even; covers xi in [2t0-8, 2t0+1031]

    double acc[4][2];
#pragma unroll
    for (int c = 0; c < 4; ++c) acc[c][0] = acc[c][1] = (double)bias[co0 + c];

    for (int ci = 0; ci < CIN; ++ci) {
        const float* xc = xb + (size_t)ci * LIN;
        __syncthreads();
        for (int idx = tid; idx < 1040; idx += 256) {
            const int xi = base + idx;
            xs[idx & 1][idx >> 1] = ((unsigned)xi < (unsigned)LIN) ? xc[xi] : 0.f;
        }
        __syncthreads();
        const float* wc = w + ((size_t)co0 * CIN + ci) * 15;
#pragma unroll
        for (int k = 0; k < 15; ++k) {
            const int p  = (k + 1) & 1;
            const int jb = (k + 1) >> 1;
            const double x0 = (double)xs[p][tid + jb];          // output t0+tid
            const double x1 = (double)xs[p][tid + 256 + jb];    // output t0+tid+256
#pragma unroll
            for (int c = 0; c < 4; ++c) {
                const double wv = (double)wc[c * CIN * 15 + k];
                acc[c][0] = fma(wv, x0, acc[c][0]);
                acc[c][1] = fma(wv, x1, acc[c][1]);
            }
        }
    }
#pragma unroll
    for (int c = 0; c < 4; ++c) {
        float* yp = y + ((size_t)b * COUT + co0 + c) * LOUT;
        const double a0 = acc[c][0], a1 = acc[c][1];
        yp[t0 + tid]       = (float)(a0 > 0.0 ? a0 : expm1(a0));
        yp[t0 + tid + 256] = (float)(a1 > 0.0 ? a1 : expm1(a1));
    }
}

// ---------------- tiled transpose: in[b][RIN][CIN_] -> out[b][CIN_][RIN] ----------------
template<int RIN, int CIN_>
__global__ __launch_bounds__(256)
void re_tr(const float* __restrict__ in, float* __restrict__ out)
{
    __shared__ float tile[32][33];
    const int c0 = blockIdx.x * 32, r0 = blockIdx.y * 32, b = blockIdx.z;
    const int lx = threadIdx.x & 31, ly = threadIdx.x >> 5;
    const float* ib = in + (size_t)b * RIN * CIN_;
    float* ob = out + (size_t)b * RIN * CIN_;
#pragma unroll
    for (int m = 0; m < 4; ++m)
        tile[ly + m * 8][lx] = ib[(size_t)(r0 + ly + m * 8) * CIN_ + c0 + lx];
    __syncthreads();
#pragma unroll
    for (int m = 0; m < 4; ++m)
        ob[(size_t)(c0 + ly + m * 8) * RIN + r0 + lx] = tile[lx][ly + m * 8];
}

// ---------------- decoder ConvTranspose1d (f32) — verbatim r11 ----------------
template<int CIN, int COUT, int LIN, int CO_PER, int ACT>   // ACT 0=ELU, 1=tanh
__global__ __launch_bounds__(256)
void re_dec(const float* __restrict__ x, const float* __restrict__ w,
            const float* __restrict__ bias, float* __restrict__ y)
{
    constexpr int LOUT = LIN * 2;
    const int u   = blockIdx.x * 256 + threadIdx.x;
    const int co0 = blockIdx.y * CO_PER;
    const int b   = blockIdx.z;

    float acc[CO_PER][2];
#pragma unroll
    for (int c = 0; c < CO_PER; ++c) acc[c][0] = acc[c][1] = bias[co0 + c];

    const float* xb = x + (size_t)b * CIN * LIN;
    for (int ci = 0; ci < CIN; ++ci) {
        const float* xc = xb + (size_t)ci * LIN;
        const float* wc = w + ((size_t)ci * COUT + co0) * 15;
#pragma unroll
        for (int dj = 0; dj < 8; ++dj) {
            const int j = u - 3 + dj;
            const float xv = ((unsigned)j < (unsigned)LIN) ? xc[j] : 0.f;
            const int ke = 13 - 2 * dj;
            const int ko = 14 - 2 * dj;
#pragma unroll
            for (int c = 0; c < CO_PER; ++c) {
                if (ke >= 0) acc[c][0] = fmaf(xv, wc[c * 15 + ke], acc[c][0]);
                acc[c][1] = fmaf(xv, wc[c * 15 + ko], acc[c][1]);
            }
        }
    }
#pragma unroll
    for (int c = 0; c < CO_PER; ++c) {
        float* yp = y + ((size_t)b * COUT + co0 + c) * LOUT + 2 * (size_t)u;
        if (ACT == 0) {
            yp[0] = acc[c][0] > 0.f ? acc[c][0] : expm1f(acc[c][0]);
            yp[1] = acc[c][1] > 0.f ? acc[c][1] : expm1f(acc[c][1]);
        } else {
            yp[0] = tanhf(acc[c][0]);
            yp[1] = tanhf(acc[c][1]);
        }
    }
}

// ---------------- prep: N32[c] = fl32( sum_f64 fl32(c_d^2) ) + zero loss ----------------
__global__ __launch_bounds__(64)
void re_prep(const float* __restrict__ cb, float* __restrict__ cnormF,
             float* __restrict__ lossp)
{
    __shared__ double red[64];
    const int rrow = blockIdx.x;
    const float* src = cb + (size_t)rrow * HID;
    const int lane = threadIdx.x;
    double s = 0.0;
#pragma unroll
    for (int m = 0; m < 8; ++m) {
        const float v = src[lane * 8 + m];
        s += (double)__fmul_rn(v, v);
    }
    red[lane] = s;
    __syncthreads();
    if (lane == 0) {
        double tot = 0.0;
        for (int i = 0; i < 64; ++i) tot += red[i];
        cnormF[rrow] = (float)tot;
        if (rrow == 0) lossp[0] = 0.f;
    }
}

// ---------------- Z pre-pass (r11 realization): 4 parts of 128 sequential d ----------------
// R row-major [32768][512].
__global__ __launch_bounds__(256)
void re_z(const float* __restrict__ R, float* __restrict__ Zrow)
{
    __shared__ double zp[64][4];
    const int tid = threadIdx.x;
    const int gr0 = blockIdx.x * 64;
    const int row = tid & 63, p = tid >> 6;
    const float* Rr = R + (size_t)(gr0 + row) * HID + p * 128;
    double s = 0.0;
    for (int i = 0; i < 128; ++i) {
        const float v = Rr[i];
        s += (double)__fmul_rn(v, v);
    }
    zp[row][p] = s;
    __syncthreads();
    if (tid < 64)
        Zrow[gr0 + tid] = (float)(((zp[tid][0] + zp[tid][1]) + zp[tid][2]) + zp[tid][3]);
}

// ---------------- f32 prefilter: per-row tile-16 minima of (N - 2M) estimate --------------
// grid (512, 8); block = 64 rows x 128 codes; thread tile 4 rows x 8 codes. R row-major.
__global__ __launch_bounds__(256)
void re_pref(const float* __restrict__ cb, const float* __restrict__ cnormF,
             const float* __restrict__ R, float* __restrict__ tileMin)
{
    __shared__ __align__(16) float Rt[32][64];
    __shared__ __align__(16) float Ct[32][128];
    const int tid = threadIdx.x;
    const int gr0 = blockIdx.x * 64;
    const int cb0 = blockIdx.y * 128;
    const float* Rbase = R + (size_t)gr0 * HID;
    const int ir = tid >> 4, jc = tid & 15;

    float acc[4][8];
#pragma unroll
    for (int r = 0; r < 4; ++r)
#pragma unroll
        for (int c = 0; c < 8; ++c) acc[r][c] = 0.f;

    for (int kc = 0; kc < 16; ++kc) {
        const int k0 = kc * 32;
        __syncthreads();
#pragma unroll
        for (int rep = 0; rep < 2; ++rep) {      // Rt[k][row] from row-major R, float4 reads
            const int row  = (tid >> 3) + 32 * rep;
            const int koff = (tid & 7) * 4;
            const float4 v = *(const float4*)(Rbase + (size_t)row * HID + k0 + koff);
            Rt[koff + 0][row] = v.x; Rt[koff + 1][row] = v.y;
            Rt[koff + 2][row] = v.z; Rt[koff + 3][row] = v.w;
        }
        {
            const int cc = tid >> 1, h = (tid & 1) * 16;
            const float* s = cb + (size_t)(cb0 + cc) * HID + k0 + h;
            const float4 v0 = *(const float4*)s;
            const float4 v1 = *(const float4*)(s + 4);
            const float4 v2 = *(const float4*)(s + 8);
            const float4 v3 = *(const float4*)(s + 12);
            Ct[h + 0][cc] = v0.x; Ct[h + 1][cc] = v0.y; Ct[h + 2][cc] = v0.z; Ct[h + 3][cc] = v0.w;
            Ct[h + 4][cc] = v1.x; Ct[h + 5][cc] = v1.y; Ct[h + 6][cc] = v1.z; Ct[h + 7][cc] = v1.w;
            Ct[h + 8][cc] = v2.x; Ct[h + 9][cc] = v2.y; Ct[h +10][cc] = v2.z; Ct[h +11][cc] = v2.w;
            Ct[h +12][cc] = v3.x; Ct[h +13][cc] = v3.y; Ct[h +14][cc] = v3.z; Ct[h +15][cc] = v3.w;
        }
        __syncthreads();

#pragma unroll
        for (int kk = 0; kk < 32; ++kk) {
            const float4 rv = *(const float4*)&Rt[kk][ir * 4];
            const float4 c0v = *(const float4*)&Ct[kk][jc * 8];
            const float4 c1v = *(const float4*)&Ct[kk][jc * 8 + 4];
            const float rr[4] = {rv.x, rv.y, rv.z, rv.w};
            const float cc8[8] = {c0v.x, c0v.y, c0v.z, c0v.w, c1v.x, c1v.y, c1v.z, c1v.w};
#pragma unroll
            for (int r = 0; r < 4; ++r)
#pragma unroll
                for (int c = 0; c < 8; ++c)
                    acc[r][c] = fmaf(rr[r], cc8[c], acc[r][c]);
        }
    }

#pragma unroll
    for (int r = 0; r < 4; ++r) {
        float m = 3.0e38f;
#pragma unroll
        for (int c = 0; c < 8; ++c) {
            const int ci = cb0 + jc * 8 + c;
            const float s = fmaf(-2.f, acc[r][c], cnormF[ci]);
            m = fminf(m, s);
        }
        const float o = __shfl_xor(m, 1, 64);
        m = fminf(m, o);
        if ((jc & 1) == 0)
            tileMin[(size_t)(gr0 + ir * 4 + r) * 64 + (cb0 >> 4) + (jc >> 1)] = m;
    }
}

// ---------------- exact rescore of candidate tiles + final code (row-major R) -------------
__global__ __launch_bounds__(256)
void re_fin(const float* __restrict__ cb, const float* __restrict__ cnormF,
            const float* __restrict__ R, const float* __restrict__ Zrow,
            const float* __restrict__ tileMin, unsigned short* __restrict__ codesOut)
{
    __shared__ float pm[64][4];
    __shared__ float rowMinS[64];
    __shared__ unsigned char tlist[64][16];
    __shared__ int tcnt[64];
    __shared__ int maxcS;
    __shared__ float bvS[64][4];
    __shared__ int   bcS[64][4];

    const int tid = threadIdx.x;
    const int gr0 = blockIdx.x * 64;
    const int row = tid & 63, p = tid >> 6;
    const float* Rr = R + (size_t)(gr0 + row) * HID;
    const float* tmr = tileMin + (size_t)(gr0 + row) * 64;

    float m = 3.0e38f;
    for (int j = 0; j < 16; ++j) m = fminf(m, tmr[p * 16 + j]);
    pm[row][p] = m;
    if (tid == 0) maxcS = 0;
    __syncthreads();
    if (tid < 64)
        rowMinS[tid] = fminf(fminf(pm[tid][0], pm[tid][1]), fminf(pm[tid][2], pm[tid][3]));
    __syncthreads();

    if (tid < 64) {
        int cnt = 0;
        const float thr_ = rowMinS[tid] + DELTA;
        const float* tr = tileMin + (size_t)(gr0 + tid) * 64;
        for (int tt = 0; tt < 64; ++tt)
            if (tr[tt] <= thr_) { if (cnt < 16) tlist[tid][cnt] = (unsigned char)tt; ++cnt; }
        if (cnt > 16) cnt = 64;
        tcnt[tid] = cnt;
        atomicMax(&maxcS, cnt);
    }
    __syncthreads();
    const int maxc = maxcS;
    const int myCnt = tcnt[row];
    const float Zr = Zrow[gr0 + row];

    float bestS = 3.0e38f; int bestC = 0x7fffffff;
    for (int li = 0; li < maxc; ++li) {
        int tt = -1;
        if (li < myCnt) tt = (myCnt <= 16) ? (int)tlist[row][li] : li;
        if (tt >= 0) {
            const float* cp = cb + (size_t)(tt * 16 + p * 4) * HID;
            double a0 = 0.0, a1 = 0.0, a2 = 0.0, a3 = 0.0;
            for (int d = 0; d < 512; ++d) {
                const double rv = (double)Rr[d];
                a0 = fma(rv, (double)cp[d],        a0);
                a1 = fma(rv, (double)cp[d + 512],  a1);
                a2 = fma(rv, (double)cp[d + 1024], a2);
                a3 = fma(rv, (double)cp[d + 1536], a3);
            }
            const double aa[4] = {a0, a1, a2, a3};
#pragma unroll
            for (int c = 0; c < 4; ++c) {
                const int ci = tt * 16 + p * 4 + c;
                const float M32 = (float)aa[c];
                const float s = __fadd_rn(__fsub_rn(Zr, __fadd_rn(M32, M32)), cnormF[ci]);
                if (s < bestS || (s == bestS && ci < bestC)) { bestS = s; bestC = ci; }
            }
        }
    }
    bvS[row][p] = bestS; bcS[row][p] = bestC;
    __syncthreads();
    if (tid < 64) {
        float mv = 3.0e38f; int mc = 0x7fffffff;
#pragma unroll
        for (int q = 0; q < 4; ++q) {
            const float v = bvS[tid][q]; const int c = bcS[tid][q];
            if (v < mv || (v == mv && c < mc)) { mv = v; mc = c; }
        }
        codesOut[gr0 + tid] = (unsigned short)mc;
    }
}

// ---------------- ST update + loss — fully coalesced (row-major R, Q) ----------------
__global__ __launch_bounds__(256)
void re_comb(const float* __restrict__ cb, const unsigned short* __restrict__ codesIn,
             float* __restrict__ R, float* __restrict__ Q,
             float* __restrict__ loss_acc, int stage)
{
    __shared__ int codes_l[64];
    const int tid = threadIdx.x;
    const int gr0 = blockIdx.x * 64;
    float* Rb = R + (size_t)gr0 * HID;
    float* Qb = Q + (size_t)gr0 * HID;

    if (tid < 64) codes_l[tid] = (int)codesIn[gr0 + tid];
    __syncthreads();

    float ls = 0.f;
    for (int e = tid; e < 64 * HID; e += 256) {
        const int row = e >> 9;                 // HID == 512
        const int c = codes_l[row];
        const float rr = Rb[e];
        const float q = cb[(size_t)c * HID + (e & 511)];
        const float diff  = __fsub_rn(q, rr);
        const float zqst  = __fadd_rn(rr, diff);
        ls = fmaf(diff, diff, ls);
        Rb[e] = __fsub_rn(rr, zqst);
        if (stage == 0) Qb[e] = zqst; else Qb[e] = __fadd_rn(Qb[e], zqst);
    }
#pragma unroll
    for (int off = 32; off; off >>= 1) ls += __shfl_down(ls, off, 64);
    if ((tid & 63) == 0) atomicAdd(loss_acc, ls);
}

// ---------------- single writer of d_out (f32), last dispatch ----------------
__global__ __launch_bounds__(256)
void re_emit(const float* __restrict__ reconF, const unsigned short* __restrict__ codes_ws,
             const float* __restrict__ loss_acc, float* __restrict__ out)
{
    const int j = blockIdx.x * 256 + threadIdx.x;
    if (j >= 524288 + 1 + NCB * 32768) return;
    if (j < 524288)       out[j] = reconF[j];
    else if (j == 524288) out[j] = loss_acc[0] * 1.25f * (1.0f / 16777216.0f);
    else                  out[j] = (float)codes_ws[j - 524289];
}

extern "C" void kernel_launch(void* const* d_in, const int* in_sizes, int n_in,
                              void* d_out, int out_size, void* d_ws, size_t ws_size,
                              hipStream_t stream)
{
    float* out = (float*)d_out;

    if (n_in != 18)                                   { re_sentinel<<<1, 256, 0, stream>>>(out, 1111.0f); return; }
    if (in_sizes[0] != 8 * 65536 || in_sizes[9] != NCB * CBS * HID ||
        in_sizes[1] != 64 * 15 || in_sizes[10] != 512 * 256 * 15)
                                                      { re_sentinel<<<1, 256, 0, stream>>>(out, 3333.0f); return; }
    if (out_size != 524288 + 1 + NCB * 32768)         { re_sentinel<<<1, 256, 0, stream>>>(out, 5555.0f); return; }
    if (ws_size < (size_t)137 * 1024 * 1024)          { re_sentinel<<<1, 256, 0, stream>>>(out, 7777.0f); return; }

    const float* audio = (const float*)d_in[0];
    const float *ew[4], *eb[4], *dw[4], *db[4];
    for (int i = 0; i < 4; ++i) { ew[i] = (const float*)d_in[1 + 2 * i]; eb[i] = (const float*)d_in[2 + 2 * i]; }
    const float* cbs = (const float*)d_in[9];
    for (int i = 0; i < 4; ++i) { dw[i] = (const float*)d_in[10 + 2 * i]; db[i] = (const float*)d_in[11 + 2 * i]; }

    // ---- workspace layout (<= 136.7 MB) ----
    char* ws = (char*)d_ws;
    float*  A        = (float*)ws;                                   // [0,64MB)
    float*  Bb       = (float*)(ws + (size_t)64 * 1024 * 1024);      // [64,128MB)
    float*  tileMin  = (float*)(ws + (size_t)128 * 1024 * 1024);     // 8MB (VQ phase)
    float*  reconF   = (float*)(ws + (size_t)128 * 1024 * 1024);     // 2MB overlay (post-VQ)
    unsigned short* codes_ws = (unsigned short*)(ws + (size_t)136 * 1024 * 1024);  // 512KB
    float*  cnormF   = (float*)(ws + (size_t)136 * 1024 * 1024 + 524288);          // 32KB
    float*  Zrow     = (float*)(ws + (size_t)136 * 1024 * 1024 + 524288 + 32768);  // 128KB
    float*  lossp    = (float*)(ws + (size_t)136 * 1024 * 1024 + 524288 + 32768 + 131072);

    re_prep<<<NCB * CBS, 64, 0, stream>>>(cbs, cnormF, lossp);

    // encoder (f64 interior, conflict-free LDS): audio -> A -> Bb -> A -> Bb(=z_col)
    re_enc<1,   64,  65536><<<dim3(64, 16,  NB), 256, 0, stream>>>(audio, ew[0], eb[0], A);
    re_enc<64,  128, 32768><<<dim3(32, 32,  NB), 256, 0, stream>>>(A,  ew[1], eb[1], Bb);
    re_enc<128, 256, 16384><<<dim3(16, 64,  NB), 256, 0, stream>>>(Bb, ew[2], eb[2], A);
    re_enc<256, 512, 8192 ><<<dim3(8,  128, NB), 256, 0, stream>>>(A,  ew[3], eb[3], Bb);

    // z_col(Bb) -> R_row(A)  [32768][512]
    re_tr<512, 4096><<<dim3(128, 16, NB), 256, 0, stream>>>(Bb, A);

    // residual VQ (row-major): R = A, Q = Bb
    for (int i = 0; i < NCB; ++i) {
        const float* cbi = cbs + (size_t)i * CBS * HID;
        const float* cni = cnormF + (size_t)i * CBS;
        re_z   <<<512, 256, 0, stream>>>(A, Zrow);
        re_pref<<<dim3(512, 8), 256, 0, stream>>>(cbi, cni, A, tileMin);
        re_fin <<<512, 256, 0, stream>>>(cbi, cni, A, Zrow, tileMin,
                                         codes_ws + (size_t)i * 32768);
        re_comb<<<512, 256, 0, stream>>>(cbi, codes_ws + (size_t)i * 32768,
                                         A, Bb, lossp, i);
    }

    // Q_row(Bb) -> Q_col(A)
    re_tr<4096, 512><<<dim3(16, 128, NB), 256, 0, stream>>>(Bb, A);

    // decoder (f32): A -> Bb -> A -> Bb -> reconF
    re_dec<512, 256, 4096,  4, 0><<<dim3(16,  64, NB), 256, 0, stream>>>(A,  dw[0], db[0], Bb);
    re_dec<256, 128, 8192,  4, 0><<<dim3(32,  32, NB), 256, 0, stream>>>(Bb, dw[1], db[1], A);
    re_dec<128, 64,  16384, 4, 0><<<dim3(64,  16, NB), 256, 0, stream>>>(A,  dw[2], db[2], Bb);
    re_dec<64,  1,   32768, 1, 1><<<dim3(128, 1,  NB), 256, 0, stream>>>(Bb, dw[3], db[3], reconF);

    // single writer of d_out, last dispatch
    re_emit<<<3073, 256, 0, stream>>>(reconF, codes_ws, lossp, out);
}